// Round 5
// baseline (1100.681 us; speedup 1.0000x reference)
//
#include <hip/hip_runtime.h>

#define DEV __device__ __forceinline__

typedef short bf16x8 __attribute__((ext_vector_type(8)));
typedef float f32x4 __attribute__((ext_vector_type(4)));
typedef unsigned int uint;

// ---------- helpers ----------
DEV unsigned short f2b(float f) {               // fp32 -> bf16 RNE
    uint u = __float_as_uint(f);
    u += 0x7fffu + ((u >> 16) & 1u);
    return (unsigned short)(u >> 16);
}
DEV uint packbf2(float a, float b) { return (uint)f2b(a) | ((uint)f2b(b) << 16); }
DEV float b2f(unsigned short s) { return __uint_as_float(((uint)s) << 16); }
DEV float b2f_lo(uint u) { return __uint_as_float(u << 16); }
DEV float b2f_hi(uint u) { return __uint_as_float(u & 0xffff0000u); }

DEV void async_cp16(const void* g, void* l) {   // global -> LDS, 16B/lane
    __builtin_amdgcn_global_load_lds(
        (const __attribute__((address_space(1))) unsigned int*)g,
        (__attribute__((address_space(3))) unsigned int*)l, 16, 0, 0);
}

DEV float quad_sum(float x) {                   // sum over 4-lane quad via DPP
    x += __int_as_float(__builtin_amdgcn_update_dpp(0, __float_as_int(x), 0xB1, 0xF, 0xF, true));
    x += __int_as_float(__builtin_amdgcn_update_dpp(0, __float_as_int(x), 0x4E, 0xF, 0xF, true));
    return x;
}

DEV float gelu_f(float u) {                     // tanh-approx gelu via sigmoid/exp
    float p = u + 0.044715f * u * u * u;
    float e = __expf(-1.5957691216f * p);
    return __fdividef(u, 1.f + e);
}

// decode 8 bf16 (uint4) -> 8 floats
DEV void dec8(uint4 p, float* o) {
    o[0] = b2f_lo(p.x); o[1] = b2f_hi(p.x); o[2] = b2f_lo(p.y); o[3] = b2f_hi(p.y);
    o[4] = b2f_lo(p.z); o[5] = b2f_hi(p.z); o[6] = b2f_lo(p.w); o[7] = b2f_hi(p.w);
}

// ---------- transpose + cast: in f32 [K][N] -> out bf16 [Npad][K], rows >= N zero ----------
__global__ __launch_bounds__(256) void transpose_cast_k(
    const float* __restrict__ in, unsigned short* __restrict__ out, int K, int N)
{
    __shared__ float tile[32][33];
    const int k0 = blockIdx.x * 32, n0 = blockIdx.y * 32;
    const int tx = threadIdx.x & 31, ty = threadIdx.x >> 5;
#pragma unroll
    for (int i = 0; i < 32; i += 8) {
        int n = n0 + tx;
        tile[ty + i][tx] = (n < N) ? in[(size_t)(k0 + ty + i) * N + n] : 0.0f;
    }
    __syncthreads();
#pragma unroll
    for (int i = 0; i < 32; i += 8) {
        out[(size_t)(n0 + ty + i) * K + (k0 + tx)] = f2b(tile[tx][ty + i]);
    }
}

// ---------- concat bias [bq|bk|bv|bbeta|0pad] -> 3200 ----------
__global__ void build_bias_k(const float* __restrict__ bq, const float* __restrict__ bk,
                             const float* __restrict__ bv, const float* __restrict__ bb,
                             float* __restrict__ outb)
{
    int i = blockIdx.x * 256 + threadIdx.x;
    if (i >= 3200) return;
    float v = 0.f;
    if (i < 1024)      v = bq[i];
    else if (i < 2048) v = bk[i - 1024];
    else if (i < 3072) v = bv[i - 2048];
    else if (i < 3088) v = bb[i - 3072];
    outb[i] = v;
}

// ---------- rmsnorm (rows of 1024) + cast to bf16 ----------
__global__ __launch_bounds__(256) void rmsnorm_cast_k(
    const float* __restrict__ x, const float* __restrict__ scale,
    unsigned short* __restrict__ out)
{
    const int row = blockIdx.x;
    const int t = threadIdx.x;
    const float4 v = *(const float4*)(x + (size_t)row * 1024 + t * 4);
    float ss = v.x * v.x + v.y * v.y + v.z * v.z + v.w * v.w;
#pragma unroll
    for (int off = 1; off < 64; off <<= 1) ss += __shfl_xor(ss, off);
    __shared__ float wsum[4];
    if ((t & 63) == 0) wsum[t >> 6] = ss;
    __syncthreads();
    const float tot = wsum[0] + wsum[1] + wsum[2] + wsum[3];
    const float inv = rsqrtf(tot * (1.0f / 1024.0f) + 1e-6f);
    const float4 sc = *(const float4*)(scale + t * 4);
    uint lo = (uint)f2b(v.x * inv * sc.x) | ((uint)f2b(v.y * inv * sc.y) << 16);
    uint hi = (uint)f2b(v.z * inv * sc.z) | ((uint)f2b(v.w * inv * sc.w) << 16);
    uint2 pkd; pkd.x = lo; pkd.y = hi;
    *(uint2*)(out + (size_t)row * 1024 + t * 4) = pkd;
}

// ---------- FLAT GEMM: C[M,N] = A[M,K](bf16) * BT[N,K](bf16)^T ----------
// No LDS in the K-loop, no barriers anywhere. Each wave owns a 64x64 tile and
// loads its MFMA fragments directly global->VGPR (the B^T layout makes the
// fragment pattern coalesced), 2-slot register pipeline for latency hiding.
// grid: x = n-block (so each XCD's %8 class sees a small B slice), y = m-block.
// MODE 0: C=f32 +bias   MODE 1: C=f32 +bias+add   MODE 2: C=bf16 gelu(+bias)   MODE 3: C=bf16 +bias
template <int MODE>
__global__ __launch_bounds__(256) void gemm_flat(
    const unsigned short* __restrict__ A, const unsigned short* __restrict__ BT,
    const float* __restrict__ bias, const float* __restrict__ add,
    void* __restrict__ Cout, int N, int K)
{
    __shared__ float ep[4 * 1088];   // epilogue scratch (MODE 2/3), per-wave 1088 f32
    const int tid = threadIdx.x;
    const int wid = tid >> 6;
    const int lane = tid & 63;
    const int n0 = blockIdx.x * 128;
    const int m0 = blockIdx.y * 128;
    const int wm = (wid & 1) * 64;
    const int wn = (wid >> 1) * 64;
    const int l16 = lane & 15;
    const int quad = lane >> 4;

    const unsigned short* Ap[4];
    const unsigned short* Bp[4];
#pragma unroll
    for (int i = 0; i < 4; i++) {
        Ap[i] = A + (size_t)(m0 + wm + i * 16 + l16) * K + quad * 8;
        Bp[i] = BT + (size_t)(n0 + wn + i * 16 + l16) * K + quad * 8;
    }

    f32x4 acc[4][4];
#pragma unroll
    for (int i = 0; i < 4; i++)
#pragma unroll
        for (int j = 0; j < 4; j++) acc[i][j] = (f32x4)0.f;

    bf16x8 a_[2][4], b_[2][4];
#pragma unroll
    for (int s = 0; s < 2; s++)
#pragma unroll
        for (int i = 0; i < 4; i++) {
            a_[s][i] = *(const bf16x8*)(Ap[i] + s * 32);
            b_[s][i] = *(const bf16x8*)(Bp[i] + s * 32);
        }

    const int KI = K >> 5;   // k-iters of 32
#pragma unroll 1
    for (int ki = 0; ki < KI - 2; ki += 2) {
#pragma unroll
        for (int i = 0; i < 4; i++)
#pragma unroll
            for (int j = 0; j < 4; j++)
                acc[i][j] = __builtin_amdgcn_mfma_f32_16x16x32_bf16(a_[0][i], b_[0][j], acc[i][j], 0, 0, 0);
#pragma unroll
        for (int i = 0; i < 4; i++) {
            a_[0][i] = *(const bf16x8*)(Ap[i] + (ki + 2) * 32);
            b_[0][i] = *(const bf16x8*)(Bp[i] + (ki + 2) * 32);
        }
#pragma unroll
        for (int i = 0; i < 4; i++)
#pragma unroll
            for (int j = 0; j < 4; j++)
                acc[i][j] = __builtin_amdgcn_mfma_f32_16x16x32_bf16(a_[1][i], b_[1][j], acc[i][j], 0, 0, 0);
#pragma unroll
        for (int i = 0; i < 4; i++) {
            a_[1][i] = *(const bf16x8*)(Ap[i] + (ki + 3) * 32);
            b_[1][i] = *(const bf16x8*)(Bp[i] + (ki + 3) * 32);
        }
    }
    // tail: last two k-iters already resident in slots 0,1
#pragma unroll
    for (int s = 0; s < 2; s++)
#pragma unroll
        for (int i = 0; i < 4; i++)
#pragma unroll
            for (int j = 0; j < 4; j++)
                acc[i][j] = __builtin_amdgcn_mfma_f32_16x16x32_bf16(a_[s][i], b_[s][j], acc[i][j], 0, 0, 0);

    if (MODE == 2 || MODE == 3) {
        // per-wave LDS transpose epilogue (same-wave DS ordering -> no barriers)
        float* epw = ep + wid * 1088;
        unsigned short* Cu = (unsigned short*)Cout;
#pragma unroll
        for (int i = 0; i < 4; i++) {
#pragma unroll
            for (int j = 0; j < 4; j++) {
                const float bv = bias[n0 + wn + j * 16 + l16];
#pragma unroll
                for (int r = 0; r < 4; r++) {
                    float v = acc[i][j][r] + bv;
                    if (MODE == 2) v = gelu_f(v);
                    epw[(j * 16 + l16) * 17 + quad * 4 + r] = v;
                }
            }
#pragma unroll
            for (int rep = 0; rep < 2; rep++) {
                const int cg = quad + 4 * rep;   // 0..7 col-group of 8
                float f[8];
#pragma unroll
                for (int m = 0; m < 8; m++) f[m] = epw[(cg * 8 + m) * 17 + l16];
                uint4 pk;
                pk.x = packbf2(f[0], f[1]); pk.y = packbf2(f[2], f[3]);
                pk.z = packbf2(f[4], f[5]); pk.w = packbf2(f[6], f[7]);
                *(uint4*)(Cu + (size_t)(m0 + wm + i * 16 + l16) * N + (n0 + wn + cg * 8)) = pk;
            }
        }
    } else {
#pragma unroll
        for (int j = 0; j < 4; j++) {
            const int cg2 = n0 + wn + j * 16 + l16;
            const float bv = bias[cg2];
#pragma unroll
            for (int i = 0; i < 4; i++) {
                const int rg0 = m0 + wm + i * 16 + quad * 4;
#pragma unroll
                for (int r = 0; r < 4; r++) {
                    size_t idx = (size_t)(rg0 + r) * N + cg2;
                    float v = acc[i][j][r] + bv;
                    if (MODE == 1) v += add[idx];
                    ((float*)Cout)[idx] = v;
                }
            }
        }
    }
}

// =====================================================================
// Chunked WY delta-rule scan, chunk L=64 (all bf16 tensors, MFMA prop).
// Tiled global layouts per (bh,ch), flat 4096 ush = 8KB:
//   Wg  : [g_d(8)][t(64)][8]   W[t][d]
//   KTg : [g_t(8)][d(64)][8]   Kn[t][d] transposed
//   ZTg : [g_t(8)][j(64)][8]   Z[t][j] transposed
//   Sall: [d(64)][j(64)]       chunk-start S
//   Yg  : [t(64)][j(64)]       Y row-major
// =====================================================================

// ---------- prep: normalize k in place (bf16 qkv), build A, solve W,Z, emit tiled layouts ----------
__global__ __launch_bounds__(256) void gdn_prep(
    unsigned short* __restrict__ qkv, unsigned short* __restrict__ Wg,
    unsigned short* __restrict__ ZTg, unsigned short* __restrict__ KTg)
{
    const int chunk = blockIdx.x, bh = blockIdx.y;
    const int b = bh >> 4, h = bh & 15;
    __shared__ float Ks[64 * 68];
    __shared__ float Ws[64 * 65];
    __shared__ float Zs[64 * 65];
    __shared__ float Asl[64 * 65];
    __shared__ float bs[64];
    const int tid = threadIdx.x;
    const int t = tid >> 2, c = tid & 3;
    unsigned short* rowp = qkv + (size_t)(b * 2048 + chunk * 64 + t) * 3200;

    float kn[16];
    {
        uint4 ka = *(const uint4*)(rowp + 1024 + h * 64 + 16 * c);
        uint4 kb = *(const uint4*)(rowp + 1024 + h * 64 + 16 * c + 8);
        dec8(ka, kn); dec8(kb, kn + 8);
    }
    float ss = 0.f;
#pragma unroll
    for (int j = 0; j < 16; j++) ss += kn[j] * kn[j];
    ss = quad_sum(ss);
    const float inv = 1.f / (sqrtf(ss) + 1e-6f);
#pragma unroll
    for (int j = 0; j < 16; j++) kn[j] *= inv;
#pragma unroll
    for (int j = 0; j < 16; j++) Ks[t * 68 + 16 * c + j] = kn[j];
    {
        uint4 p0, p1;
        p0.x = packbf2(kn[0], kn[1]);  p0.y = packbf2(kn[2], kn[3]);
        p0.z = packbf2(kn[4], kn[5]);  p0.w = packbf2(kn[6], kn[7]);
        p1.x = packbf2(kn[8], kn[9]);  p1.y = packbf2(kn[10], kn[11]);
        p1.z = packbf2(kn[12], kn[13]); p1.w = packbf2(kn[14], kn[15]);
        *(uint4*)(rowp + 1024 + h * 64 + 16 * c) = p0;
        *(uint4*)(rowp + 1024 + h * 64 + 16 * c + 8) = p1;
    }
    if (c == 0) bs[t] = 1.f / (1.f + __expf(-b2f(rowp[3072 + h])));
    __syncthreads();

    const float beta = bs[t];
#pragma unroll
    for (int j = 0; j < 16; j++) Ws[t * 65 + 16 * c + j] = beta * kn[j];
    {
        float vv[16];
        uint4 va = *(const uint4*)(rowp + 2048 + h * 64 + 16 * c);
        uint4 vb = *(const uint4*)(rowp + 2048 + h * 64 + 16 * c + 8);
        dec8(va, vv); dec8(vb, vv + 8);
#pragma unroll
        for (int j = 0; j < 16; j++) Zs[t * 65 + 16 * c + j] = beta * vv[j];
    }
    __syncthreads();

    {
        const int tt = tid >> 4, sx = tid & 15;
        float dm[4][4];
#pragma unroll
        for (int i = 0; i < 4; i++)
#pragma unroll
            for (int j = 0; j < 4; j++) dm[i][j] = 0.f;
        for (int d = 0; d < 64; d++) {
            float kt[4], ksv[4];
#pragma unroll
            for (int i = 0; i < 4; i++) kt[i] = Ks[(4 * tt + i) * 68 + d];
#pragma unroll
            for (int j = 0; j < 4; j++) ksv[j] = Ks[(4 * sx + j) * 68 + d];
#pragma unroll
            for (int i = 0; i < 4; i++)
#pragma unroll
                for (int j = 0; j < 4; j++) dm[i][j] += kt[i] * ksv[j];
        }
#pragma unroll
        for (int i = 0; i < 4; i++)
#pragma unroll
            for (int j = 0; j < 4; j++) {
                int T = 4 * tt + i, S_ = 4 * sx + j;
                Asl[T * 65 + S_] = (S_ < T) ? bs[T] * dm[i][j] : 0.f;
            }
    }
    __syncthreads();

    {
        const int wid = tid >> 6, lane = tid & 63;
        for (int qi = 0; qi < 4; qi++) {
            if (qi > 0) {
                const int tb = qi * 16 + wid * 4;
                float aw[4], az[4];
#pragma unroll
                for (int i = 0; i < 4; i++) { aw[i] = Ws[(tb + i) * 65 + lane]; az[i] = Zs[(tb + i) * 65 + lane]; }
                for (int s = 0; s < qi * 16; s++) {
                    float wsv = Ws[s * 65 + lane], zsv = Zs[s * 65 + lane];
#pragma unroll
                    for (int i = 0; i < 4; i++) {
                        float a = Asl[(tb + i) * 65 + s];
                        aw[i] -= a * wsv; az[i] -= a * zsv;
                    }
                }
#pragma unroll
                for (int i = 0; i < 4; i++) { Ws[(tb + i) * 65 + lane] = aw[i]; Zs[(tb + i) * 65 + lane] = az[i]; }
            }
            __syncthreads();
            if (wid == 0) {
                for (int T = qi * 16; T < qi * 16 + 16; T++) {
                    float a_ = Ws[T * 65 + lane];
                    for (int s = qi * 16; s < T; s++) a_ -= Asl[T * 65 + s] * Ws[s * 65 + lane];
                    Ws[T * 65 + lane] = a_;
                }
            } else if (wid == 1) {
                for (int T = qi * 16; T < qi * 16 + 16; T++) {
                    float a_ = Zs[T * 65 + lane];
                    for (int s = qi * 16; s < T; s++) a_ -= Asl[T * 65 + s] * Zs[s * 65 + lane];
                    Zs[T * 65 + lane] = a_;
                }
            }
            __syncthreads();
        }
    }

    const size_t cbase = ((size_t)bh * 32 + chunk) * 4096;
    {
#pragma unroll
        for (int half = 0; half < 2; half++) {
            uint4 w4;
            w4.x = packbf2(Ws[t * 65 + 16 * c + half * 8 + 0], Ws[t * 65 + 16 * c + half * 8 + 1]);
            w4.y = packbf2(Ws[t * 65 + 16 * c + half * 8 + 2], Ws[t * 65 + 16 * c + half * 8 + 3]);
            w4.z = packbf2(Ws[t * 65 + 16 * c + half * 8 + 4], Ws[t * 65 + 16 * c + half * 8 + 5]);
            w4.w = packbf2(Ws[t * 65 + 16 * c + half * 8 + 6], Ws[t * 65 + 16 * c + half * 8 + 7]);
            *(uint4*)(Wg + cbase + (size_t)((2 * c + half) * 64 + t) * 8) = w4;
        }
    }
    {
        const int jj = tid >> 2, tq = tid & 3;
#pragma unroll
        for (int half = 0; half < 2; half++) {
            uint4 z4;
            int i0 = half * 8;
            z4.x = packbf2(Zs[(16 * tq + i0 + 0) * 65 + jj], Zs[(16 * tq + i0 + 1) * 65 + jj]);
            z4.y = packbf2(Zs[(16 * tq + i0 + 2) * 65 + jj], Zs[(16 * tq + i0 + 3) * 65 + jj]);
            z4.z = packbf2(Zs[(16 * tq + i0 + 4) * 65 + jj], Zs[(16 * tq + i0 + 5) * 65 + jj]);
            z4.w = packbf2(Zs[(16 * tq + i0 + 6) * 65 + jj], Zs[(16 * tq + i0 + 7) * 65 + jj]);
            *(uint4*)(ZTg + cbase + (size_t)((2 * tq + half) * 64 + jj) * 8) = z4;
        }
    }
    {
        const int dd = tid >> 2, tq = tid & 3;
#pragma unroll
        for (int half = 0; half < 2; half++) {
            uint4 k4;
            int i0 = half * 8;
            k4.x = packbf2(Ks[(16 * tq + i0 + 0) * 68 + dd], Ks[(16 * tq + i0 + 1) * 68 + dd]);
            k4.y = packbf2(Ks[(16 * tq + i0 + 2) * 68 + dd], Ks[(16 * tq + i0 + 3) * 68 + dd]);
            k4.z = packbf2(Ks[(16 * tq + i0 + 4) * 68 + dd], Ks[(16 * tq + i0 + 5) * 68 + dd]);
            k4.w = packbf2(Ks[(16 * tq + i0 + 6) * 68 + dd], Ks[(16 * tq + i0 + 7) * 68 + dd]);
            *(uint4*)(KTg + cbase + (size_t)((2 * tq + half) * 64 + dd) * 8) = k4;
        }
    }
}

// ---------- prop (MFMA): 64 blocks (bh), 4 waves; wave w owns j-rows 16w..16w+15 ----------
__global__ __launch_bounds__(256, 1) void gdn_prop_mfma(
    const unsigned short* __restrict__ Wg, const unsigned short* __restrict__ KTg,
    const unsigned short* __restrict__ ZTg, unsigned short* __restrict__ Sall,
    unsigned short* __restrict__ Yg)
{
    const int bh = blockIdx.x;
    __shared__ unsigned short WbU[4096];
    __shared__ unsigned short KTbU[4096];
    __shared__ unsigned short ZTbU[4096];
    __shared__ unsigned short SbU[4096];
    const int tid = threadIdx.x;
    const int wid = tid >> 6;
    const int lane = tid & 63;
    const int l16 = lane & 15, quad = lane >> 4;

    f32x4 Sacc[4];
#pragma unroll
    for (int dt = 0; dt < 4; dt++) Sacc[dt] = (f32x4)0.f;

    for (int ch = 0; ch < 32; ch++) {
        const size_t cbase = ((size_t)bh * 32 + ch) * 4096;
#pragma unroll
        for (int p = 0; p < 2; p++) {
            const int n = wid * 2 + p;
            async_cp16(Wg + cbase + n * 512 + lane * 8, &WbU[n * 512]);
            async_cp16(KTg + cbase + n * 512 + lane * 8, &KTbU[n * 512]);
            async_cp16(ZTg + cbase + n * 512 + lane * 8, &ZTbU[n * 512]);
        }
#pragma unroll
        for (int dt = 0; dt < 4; dt++) {
#pragma unroll
            for (int r = 0; r < 4; r++) {
                const int j = wid * 16 + quad * 4 + r;
                SbU[((2 * dt + (l16 >> 3)) * 64 + j) * 8 + (l16 & 7)] = f2b(Sacc[dt][r]);
            }
            const int d = dt * 16 + l16;
            uint2 sp;
            sp.x = packbf2(Sacc[dt][0], Sacc[dt][1]);
            sp.y = packbf2(Sacc[dt][2], Sacc[dt][3]);
            *(uint2*)(Sall + cbase + d * 64 + wid * 16 + quad * 4) = sp;
        }
        __syncthreads();

        f32x4 t1[4];
#pragma unroll
        for (int tt = 0; tt < 4; tt++) t1[tt] = (f32x4)0.f;
#pragma unroll
        for (int kh = 0; kh < 2; kh++) {
            const int g = kh * 4 + quad;
            bf16x8 afr = *(const bf16x8*)&SbU[(g * 64 + wid * 16 + l16) * 8];
#pragma unroll
            for (int tt = 0; tt < 4; tt++) {
                bf16x8 bfr = *(const bf16x8*)&WbU[(g * 64 + tt * 16 + l16) * 8];
                t1[tt] = __builtin_amdgcn_mfma_f32_16x16x32_bf16(afr, bfr, t1[tt], 0, 0, 0);
            }
        }
#pragma unroll
        for (int tt = 0; tt < 4; tt++) {
            const int t = tt * 16 + l16;
            const int gb = (t >> 3) * 64;
            unsigned short ybf[4];
#pragma unroll
            for (int r = 0; r < 4; r++) {
                const int j = wid * 16 + quad * 4 + r;
                const float z = b2f(ZTbU[(gb + j) * 8 + (t & 7)]);
                ybf[r] = f2b(z - t1[tt][r]);
            }
#pragma unroll
            for (int r = 0; r < 4; r++) {
                const int j = wid * 16 + quad * 4 + r;
                ZTbU[(gb + j) * 8 + (t & 7)] = ybf[r];
            }
            uint2 yp;
            yp.x = (uint)ybf[0] | ((uint)ybf[1] << 16);
            yp.y = (uint)ybf[2] | ((uint)ybf[3] << 16);
            *(uint2*)(Yg + cbase + t * 64 + wid * 16 + quad * 4) = yp;
        }
#pragma unroll
        for (int kh = 0; kh < 2; kh++) {
            const int g = kh * 4 + quad;
            bf16x8 afr = *(const bf16x8*)&ZTbU[(g * 64 + wid * 16 + l16) * 8];
#pragma unroll
            for (int dt = 0; dt < 4; dt++) {
                bf16x8 bfr = *(const bf16x8*)&KTbU[(g * 64 + dt * 16 + l16) * 8];
                Sacc[dt] = __builtin_amdgcn_mfma_f32_16x16x32_bf16(afr, bfr, Sacc[dt], 0, 0, 0);
            }
        }
        __syncthreads();
    }
}

// ---------- output: per (bh, chunk): O = Q S_c^T + tril(Q Kn^T) Y ----------
__global__ __launch_bounds__(256) void gdn_out(
    const unsigned short* __restrict__ qkv, const unsigned short* __restrict__ Yg,
    const unsigned short* __restrict__ Sall, unsigned short* __restrict__ attn)
{
    const int chunk = blockIdx.x, bh = blockIdx.y;
    const int b = bh >> 4, h = bh & 15;
    __shared__ float Qf[64 * 68];
    __shared__ float SfT[64 * 68];
    __shared__ float Ms[64 * 65];
    __shared__ uint Kp[64 * 33];
    __shared__ uint Yp[64 * 34];
    const int tid = threadIdx.x;
    const int t = tid >> 2, c = tid & 3;
    const size_t cbase = ((size_t)bh * 32 + chunk) * 4096;

    {
        const unsigned short* rowp = qkv + (size_t)(b * 2048 + chunk * 64 + t) * 3200;
        float qv[16];
        uint4 qa = *(const uint4*)(rowp + h * 64 + 16 * c);
        uint4 qb = *(const uint4*)(rowp + h * 64 + 16 * c + 8);
        dec8(qa, qv); dec8(qb, qv + 8);
#pragma unroll
        for (int m = 0; m < 16; m++) Qf[t * 68 + 16 * c + m] = qv[m];
        uint4 ka = *(const uint4*)(rowp + 1024 + h * 64 + 16 * c);
        uint4 kb = *(const uint4*)(rowp + 1024 + h * 64 + 16 * c + 8);
        Kp[t * 33 + 8 * c + 0] = ka.x; Kp[t * 33 + 8 * c + 1] = ka.y;
        Kp[t * 33 + 8 * c + 2] = ka.z; Kp[t * 33 + 8 * c + 3] = ka.w;
        Kp[t * 33 + 8 * c + 4] = kb.x; Kp[t * 33 + 8 * c + 5] = kb.y;
        Kp[t * 33 + 8 * c + 6] = kb.z; Kp[t * 33 + 8 * c + 7] = kb.w;
        const unsigned short* yrow = Yg + cbase + t * 64 + 16 * c;
        uint4 ya = *(const uint4*)yrow;
        uint4 yb = *(const uint4*)(yrow + 8);
        Yp[t * 34 + 8 * c + 0] = ya.x; Yp[t * 34 + 8 * c + 1] = ya.y;
        Yp[t * 34 + 8 * c + 2] = ya.z; Yp[t * 34 + 8 * c + 3] = ya.w;
        Yp[t * 34 + 8 * c + 4] = yb.x; Yp[t * 34 + 8 * c + 5] = yb.y;
        Yp[t * 34 + 8 * c + 6] = yb.z; Yp[t * 34 + 8 * c + 7] = yb.w;
        const unsigned short* srow = Sall + cbase + t * 64 + 16 * c;
        float sv[16];
        uint4 sa = *(const uint4*)srow;
        uint4 sb = *(const uint4*)(srow + 8);
        dec8(sa, sv); dec8(sb, sv + 8);
#pragma unroll
        for (int m = 0; m < 16; m++) SfT[t * 68 + 16 * c + m] = sv[m];
    }
    __syncthreads();

    const int tt = tid >> 4, sx = tid & 15;
    {
        float dm[4][4];
#pragma unroll
        for (int i = 0; i < 4; i++)
#pragma unroll
            for (int j = 0; j < 4; j++) dm[i][j] = 0.f;
        for (int p = 0; p < 32; p++) {
            float q0[4], q1[4];
#pragma unroll
            for (int i = 0; i < 4; i++) {
                q0[i] = Qf[(4 * tt + i) * 68 + 2 * p];
                q1[i] = Qf[(4 * tt + i) * 68 + 2 * p + 1];
            }
#pragma unroll
            for (int j = 0; j < 4; j++) {
                uint kp = Kp[(4 * sx + j) * 33 + p];
                float kk0 = b2f_lo(kp), kk1 = b2f_hi(kp);
#pragma unroll
                for (int i = 0; i < 4; i++) dm[i][j] += q0[i] * kk0 + q1[i] * kk1;
            }
        }
#pragma unroll
        for (int i = 0; i < 4; i++)
#pragma unroll
            for (int j = 0; j < 4; j++) {
                int T = 4 * tt + i, S_ = 4 * sx + j;
                Ms[T * 65 + S_] = (S_ <= T) ? dm[i][j] : 0.f;
            }
    }
    __syncthreads();

    {
        float o[4][4];
#pragma unroll
        for (int i = 0; i < 4; i++)
#pragma unroll
            for (int j = 0; j < 4; j++) o[i][j] = 0.f;
        for (int d = 0; d < 64; d++) {
            float qv[4];
#pragma unroll
            for (int i = 0; i < 4; i++) qv[i] = Qf[(4 * tt + i) * 68 + d];
#pragma unroll
            for (int j = 0; j < 4; j++) {
                float sv = SfT[d * 68 + 4 * sx + j];
#pragma unroll
                for (int i = 0; i < 4; i++) o[i][j] += qv[i] * sv;
            }
        }
        for (int s = 0; s < 64; s++) {
            float mv[4];
#pragma unroll
            for (int i = 0; i < 4; i++) mv[i] = Ms[(4 * tt + i) * 65 + s];
            uint2 yp2 = *(const uint2*)&Yp[s * 34 + 2 * sx];
            float yv0 = b2f_lo(yp2.x), yv1 = b2f_hi(yp2.x), yv2 = b2f_lo(yp2.y), yv3 = b2f_hi(yp2.y);
#pragma unroll
            for (int i = 0; i < 4; i++) {
                o[i][0] += mv[i] * yv0; o[i][1] += mv[i] * yv1;
                o[i][2] += mv[i] * yv2; o[i][3] += mv[i] * yv3;
            }
        }
#pragma unroll
        for (int i = 0; i < 4; i++) {
            uint2 op; op.x = packbf2(o[i][0], o[i][1]); op.y = packbf2(o[i][2], o[i][3]);
            *(uint2*)(attn + (size_t)(b * 2048 + chunk * 64 + 4 * tt + i) * 1024 + h * 64 + 4 * sx) = op;
        }
    }
}

// ---------- workspace layout (bytes) ----------
static constexpr size_t OFF_H     = 0;                          // 16,777,216  hbuf bf16 / Sall bf16
static constexpr size_t OFF_WQKVT = OFF_H + 16777216;           //  6,553,600
static constexpr size_t OFF_WOT   = OFF_WQKVT + 6553600;        //  2,097,152
static constexpr size_t OFF_W1T   = OFF_WOT + 2097152;          //  8,388,608
static constexpr size_t OFF_W2T   = OFF_W1T + 8388608;          //  8,388,608
static constexpr size_t OFF_BIAS  = OFF_W2T + 8388608;          //     16,384
static constexpr size_t OFF_QKV   = OFF_BIAS + 16384;           // 67,108,864  qkv bf16 / gbuf bf16
static constexpr size_t OFF_ATTN  = OFF_QKV + 67108864;         // 16,777,216  bf16
static constexpr size_t OFF_Y1    = OFF_ATTN + 16777216;        // 33,554,432  y1 f32 / (ZTg+KTg bf16)
static constexpr size_t OFF_WG    = OFF_Y1 + 33554432;          // 16,777,216  Wg bf16
static constexpr size_t OFF_YG    = OFF_WG + 16777216;          // 16,777,216  Yg bf16

extern "C" void kernel_launch(void* const* d_in, const int* in_sizes, int n_in,
                              void* d_out, int out_size, void* d_ws, size_t ws_size,
                              hipStream_t stream)
{
    const float* x     = (const float*)d_in[0];
    const float* wq    = (const float*)d_in[1];
    const float* bq    = (const float*)d_in[2];
    const float* wk    = (const float*)d_in[3];
    const float* bk    = (const float*)d_in[4];
    const float* wv    = (const float*)d_in[5];
    const float* bv    = (const float*)d_in[6];
    const float* wbeta = (const float*)d_in[7];
    const float* bbeta = (const float*)d_in[8];
    const float* wo    = (const float*)d_in[9];
    const float* bo    = (const float*)d_in[10];
    const float* w1    = (const float*)d_in[11];
    const float* b1    = (const float*)d_in[12];
    const float* w2    = (const float*)d_in[13];
    const float* b2    = (const float*)d_in[14];
    const float* ln1   = (const float*)d_in[15];
    const float* ln2   = (const float*)d_in[16];

    char* ws = (char*)d_ws;
    unsigned short* hbuf  = (unsigned short*)(ws + OFF_H);
    unsigned short* Sall  = (unsigned short*)(ws + OFF_H);
    unsigned short* wqkvT = (unsigned short*)(ws + OFF_WQKVT);
    unsigned short* woT   = (unsigned short*)(ws + OFF_WOT);
    unsigned short* w1T   = (unsigned short*)(ws + OFF_W1T);
    unsigned short* w2T   = (unsigned short*)(ws + OFF_W2T);
    float*          biasc = (float*)(ws + OFF_BIAS);
    unsigned short* qkvU  = (unsigned short*)(ws + OFF_QKV);
    unsigned short* gbuf  = (unsigned short*)(ws + OFF_QKV);
    unsigned short* attn  = (unsigned short*)(ws + OFF_ATTN);
    float*          y1    = (float*)(ws + OFF_Y1);
    unsigned short* ZTg   = (unsigned short*)(ws + OFF_Y1);
    unsigned short* KTg   = (unsigned short*)(ws + OFF_Y1 + 16777216);
    unsigned short* Wg    = (unsigned short*)(ws + OFF_WG);
    unsigned short* Yg    = (unsigned short*)(ws + OFF_YG);
    float*          out   = (float*)d_out;

    // weight transpose+cast (B^T bf16 operands)
    transpose_cast_k<<<dim3(32, 32), 256, 0, stream>>>(wq, wqkvT,               1024, 1024);
    transpose_cast_k<<<dim3(32, 32), 256, 0, stream>>>(wk, wqkvT + 1024 * 1024, 1024, 1024);
    transpose_cast_k<<<dim3(32, 32), 256, 0, stream>>>(wv, wqkvT + 2048 * 1024, 1024, 1024);
    transpose_cast_k<<<dim3(32, 4),  256, 0, stream>>>(wbeta, wqkvT + 3072 * 1024, 1024, 16);
    transpose_cast_k<<<dim3(32, 32), 256, 0, stream>>>(wo, woT, 1024, 1024);
    transpose_cast_k<<<dim3(32, 128), 256, 0, stream>>>(w1, w1T, 1024, 4096);
    transpose_cast_k<<<dim3(128, 32), 256, 0, stream>>>(w2, w2T, 4096, 1024);
    build_bias_k<<<13, 256, 0, stream>>>(bq, bk, bv, bbeta, biasc);

    // layer
    rmsnorm_cast_k<<<8192, 256, 0, stream>>>(x, ln1, hbuf);
    gemm_flat<3><<<dim3(25, 64), 256, 0, stream>>>(hbuf, wqkvT, biasc, nullptr, qkvU, 3200, 1024);
    gdn_prep<<<dim3(32, 64), 256, 0, stream>>>(qkvU, Wg, ZTg, KTg);
    gdn_prop_mfma<<<64, 256, 0, stream>>>(Wg, KTg, ZTg, Sall, Yg);
    gdn_out<<<dim3(32, 64), 256, 0, stream>>>(qkvU, Yg, Sall, attn);
    gemm_flat<1><<<dim3(8, 64), 256, 0, stream>>>(attn, woT, bo, x, y1, 1024, 1024);
    rmsnorm_cast_k<<<8192, 256, 0, stream>>>(y1, ln2, hbuf);
    gemm_flat<2><<<dim3(32, 64), 256, 0, stream>>>(hbuf, w1T, b1, nullptr, gbuf, 4096, 1024);
    gemm_flat<1><<<dim3(8, 64), 256, 0, stream>>>(gbuf, w2T, b2, y1, out, 1024, 4096);
}